// Round 1
// baseline (859.267 us; speedup 1.0000x reference)
//
#include <hip/hip_runtime.h>

// NearestMean: out = labels[searchsorted(thresholds, X, side='right')]
// X: fp32, 142,848,000 elems. thresholds: 3 fp32. labels: 4 int32. out: int32.
// Memory-bound streaming kernel: float4 in, int4 out, 16B/lane coalesced.

__global__ __launch_bounds__(256) void NearestMean_kernel(
    const float4* __restrict__ x4,
    const float* __restrict__ thr,
    const int* __restrict__ labs,
    int4* __restrict__ out4,
    const float* __restrict__ x_tail,   // scalar view for tail
    int* __restrict__ out_tail,
    long long n4, long long n_tail)     // n_tail = n - 4*n4 (0..3)
{
    const float t0 = thr[0], t1 = thr[1], t2 = thr[2];
    const int   l0 = labs[0], l1 = labs[1], l2 = labs[2], l3 = labs[3];

    long long i = (long long)blockIdx.x * blockDim.x + threadIdx.x;
    if (i < n4) {
        float4 v = x4[i];
        int4 o;
        o.x = v.x >= t2 ? l3 : (v.x >= t1 ? l2 : (v.x >= t0 ? l1 : l0));
        o.y = v.y >= t2 ? l3 : (v.y >= t1 ? l2 : (v.y >= t0 ? l1 : l0));
        o.z = v.z >= t2 ? l3 : (v.z >= t1 ? l2 : (v.z >= t0 ? l1 : l0));
        o.w = v.w >= t2 ? l3 : (v.w >= t1 ? l2 : (v.w >= t0 ? l1 : l0));
        out4[i] = o;
    }
    // Tail (n not divisible by 4 — not the case here, but be safe).
    if (i < n_tail) {
        float v = x_tail[4 * n4 + i];
        out_tail[4 * n4 + i] =
            v >= t2 ? l3 : (v >= t1 ? l2 : (v >= t0 ? l1 : l0));
    }
}

extern "C" void kernel_launch(void* const* d_in, const int* in_sizes, int n_in,
                              void* d_out, int out_size, void* d_ws, size_t ws_size,
                              hipStream_t stream) {
    const float* X    = (const float*)d_in[0];
    const float* thr  = (const float*)d_in[1];
    const int*   labs = (const int*)d_in[2];
    int* out = (int*)d_out;

    long long n = (long long)in_sizes[0];
    long long n4 = n / 4;
    long long n_tail = n - 4 * n4;

    int block = 256;
    long long work = n4 > 0 ? n4 : 1;
    long long grid = (work + block - 1) / block;

    NearestMean_kernel<<<(dim3)(unsigned)grid, block, 0, stream>>>(
        (const float4*)X, thr, labs, (int4*)out, X, out, n4, n_tail);
}